// Round 1
// baseline (212.020 us; speedup 1.0000x reference)
//
#include <hip/hip_runtime.h>

#define HH 192
#define WW 192
#define CC 16
#define NBATCH 8
#define TH 30
#define TW 24
#define RS 40    // staged plane row stride (floats); 160 B, 16B-aligned
#define RSS 24   // rowsum row stride (floats); 96 B, 16B-aligned

// Block: 256 threads = 32 corr-rows x 8 col-groups (4 cols each).
// Each block: one batch b, one 30x24 output tile, one oy in [-4,4].
// corr rows yy = -1..30 (32), corr cols xs = -4..27 (8 aligned groups of 4;
// only -1..24 are actually needed, alignment forces the rest).
__global__ __launch_bounds__(256, 4)
void noise_corr_kernel(const float* __restrict__ noise, float* __restrict__ out) {
    __shared__ float plane[36 * RS];         // one channel, up to 36 rows x 40 cols
    __shared__ float rsum[9 * 32 * RSS];     // rowsum: 9 ox-planes x 32 rows x 24 cols

    const int tid = threadIdx.x;
    const int r = tid >> 3;            // 0..31  -> corr row yy = r-1
    const int g = tid & 7;             // 0..7   -> cols xs = 4g-4
    const int bx = blockIdx.x & 7;     // 0..7  (192/24 = 8 exact)
    const int by = blockIdx.x >> 3;    // 0..6  (ceil(192/30) = 7, last partial)
    const int oy = (int)blockIdx.y - 4;
    const int b  = blockIdx.z;

    const int y0 = by * TH;
    const int x0 = bx * TW;
    const int yy = r - 1;
    const int xs = (g << 2) - 4;

    // staged row window: union of center rows [-1,30] and shifted rows [oy-1,30+oy]
    const int rmin = (oy < 0) ? (oy - 1) : -1;
    const int NR   = 32 + (oy < 0 ? -oy : oy);   // <= 36
    const int gys  = y0 + rmin;                  // global y of plane row 0
    const int gxs  = x0 - 8;                     // global x of plane col 0 (40 cols)

    const float* nb = noise + (size_t)b * CC * HH * WW;

    float acc[9][4];
    #pragma unroll
    for (int o = 0; o < 9; ++o) {
        acc[o][0] = 0.f; acc[o][1] = 0.f; acc[o][2] = 0.f; acc[o][3] = 0.f;
    }

    const int ci = yy - rmin;        // center row index in plane
    const int si = yy + oy - rmin;   // shifted row index in plane
    const int nitems = NR * 10;      // 10 float4-quads per 40-col row

    for (int c = 0; c < CC; ++c) {
        __syncthreads();             // previous channel's readers done
        const float* src = nb + c * HH * WW;
        for (int i = tid; i < nitems; i += 256) {
            const int rr = i / 10;
            const int q  = i - rr * 10;
            const int gy = gys + rr;
            const int gx = gxs + (q << 2);
            float4 v = make_float4(0.f, 0.f, 0.f, 0.f);
            if ((unsigned)gy < HH) {
                const float* p = src + gy * WW + gx;
                if (gx >= 0 && gx + 3 < WW) {
                    v = *(const float4*)p;           // gx aligned to 4 floats
                } else {
                    if ((unsigned)(gx + 0) < WW) v.x = p[0];
                    if ((unsigned)(gx + 1) < WW) v.y = p[1];
                    if ((unsigned)(gx + 2) < WW) v.z = p[2];
                    if ((unsigned)(gx + 3) < WW) v.w = p[3];
                }
            }
            *(float4*)&plane[rr * RS + (q << 2)] = v;
        }
        __syncthreads();

        // center: cols xs..xs+3  -> plane col xs+8  (aligned, 4..32)
        const float4 cen4 = *(const float4*)&plane[ci * RS + (xs + 8)];
        // shifted: cols xs-4..xs+7 -> plane cols xs+4..xs+15 (3 aligned float4)
        float sh[12];
        *(float4*)&sh[0] = *(const float4*)&plane[si * RS + (xs + 4)];
        *(float4*)&sh[4] = *(const float4*)&plane[si * RS + (xs + 8)];
        *(float4*)&sh[8] = *(const float4*)&plane[si * RS + (xs + 12)];
        const float cen[4] = {cen4.x, cen4.y, cen4.z, cen4.w};
        #pragma unroll
        for (int o = 0; o < 9; ++o) {       // o = ox+4
            #pragma unroll
            for (int j = 0; j < 4; ++j) {
                acc[o][j] += cen[j] * sh[o + j];   // shifted col xs+j+(o-4) = sh[o+j]
            }
        }
    }

    // rowsum along x: rs(x) = corr(x-1)+corr(x)+corr(x+1).
    // Lane layout: 8 groups per row, rows never cross wave boundary (64/8=8).
    #pragma unroll
    for (int o = 0; o < 9; ++o) {
        const float left  = __shfl_up(acc[o][3], 1);    // g-1's corr at xs-1
        const float right = __shfl_down(acc[o][0], 1);  // g+1's corr at xs+4
        const float a0 = acc[o][0], a1 = acc[o][1], a2 = acc[o][2], a3 = acc[o][3];
        float4 rsv;
        rsv.x = left + a0 + a1;
        rsv.y = a0 + a1 + a2;
        rsv.z = a1 + a2 + a3;
        rsv.w = a2 + a3 + right;
        if (g >= 1 && g <= 6) {   // covers x = 0..23
            *(float4*)&rsum[(o * 32 + r) * RSS + ((g - 1) << 2)] = rsv;
        }
    }
    __syncthreads();

    // colsum + store: out(y,x) = (rs(y-1,x)+rs(y,x)+rs(y+1,x)) / 144
    const float inv = 1.0f / 144.0f;
    float* ob = out + ((size_t)b * 81 + (size_t)(oy + 4) * 9) * (HH * WW);
    for (int i = tid; i < 9 * TH * TW; i += 256) {
        const int x  = i % TW;
        const int t2 = i / TW;
        const int y  = t2 % TH;
        const int o  = t2 / TH;
        const int gy = y0 + y;
        if (gy < HH) {
            const float* rp = &rsum[(o * 32 + y) * RSS + x];  // rows y,y+1,y+2 = corr y-1,y,y+1
            const float s = rp[0] + rp[RSS] + rp[2 * RSS];
            ob[((size_t)o * HH + gy) * WW + (x0 + x)] = s * inv;
        }
    }
}

extern "C" void kernel_launch(void* const* d_in, const int* in_sizes, int n_in,
                              void* d_out, int out_size, void* d_ws, size_t ws_size,
                              hipStream_t stream) {
    const float* noise = (const float*)d_in[0];
    float* out = (float*)d_out;
    dim3 grid(56, 9, NBATCH);   // (8 bx * 7 by), 9 oy, 8 batches
    noise_corr_kernel<<<grid, 256, 0, stream>>>(noise, out);
}

// Round 3
// 165.849 us; speedup vs baseline: 1.2784x; 1.2784x over previous
//
#include <hip/hip_runtime.h>

#define HH 192
#define WW 192
#define CC 16
#define HW (HH * WW)
#define TH 30
#define TW 24
#define RS 44               // plane row stride in floats = 11 float4 chunks
#define PCHUNKS 512         // chunks per plane buffer = 256 threads x 2 (ALL DMA'd)
#define PLANEF (PCHUNKS*4)  // 2048 floats per buffer
#define RSS 28              // rowsum row stride floats

// 16B of guaranteed zeros in global memory: OOB lanes DMA from here so the
// global_load_lds is exec-uniform (lane 0 always active -> correct wave base).
__device__ float g_zero16[4] = {0.f, 0.f, 0.f, 0.f};

__device__ __forceinline__ void gload16(const void* g, void* l) {
    __builtin_amdgcn_global_load_lds(
        (const __attribute__((address_space(1))) void*)g,
        (__attribute__((address_space(3))) void*)l, 16, 0, 0);
}

// Block: 256 threads = 32 corr-rows x 8 col-groups(4 cols).
// Each block: one batch, one 30x24 EXTENDED tile (ye=-4+30*by, xe=-4+24*bx),
// one oy-group: grp0 -> oy {-4,-3,-2}, grp1 -> oy {-1,0}.
// Symmetry: out_{-o}(y+oy, x+ox) = out_o(y,x) => mirror-write oy>0 planes.
__global__ __launch_bounds__(256, 3)
void noise_corr_kernel(const float* __restrict__ noise, float* __restrict__ out) {
    __shared__ float planes[2 * PLANEF];   // double-buffered DMA dest (16 KB)
    __shared__ float rsum[9 * 32 * RSS];   // 9 ox x 32 corr-rows x 24 cols (31.5 KB)

    const int tid = threadIdx.x;
    const int r   = tid >> 3;          // 0..31 -> corr row yy = r-1
    const int g   = tid & 7;           // 0..7  -> cols xs = 4g-4
    const int bx  = blockIdx.x % 9;
    const int by  = blockIdx.x / 9;
    const int grp = blockIdx.y;
    const int b   = blockIdx.z;

    const int oymin = grp ? -1 : -4;
    const int NOY   = grp ? 2 : 3;
    const int rmin  = oymin - 1;
    const int NR    = TH + 2 - oymin;  // 36 (grp0) / 33 (grp1)
    const int nitems = NR * 11;        // used float4 chunks (<= 512)

    const int y0 = -4 + by * TH;       // extended tile origin
    const int x0 = -4 + bx * TW;
    const int yy = r - 1;
    const int xs = (g << 2) - 4;

    const float* nb = noise + (size_t)b * CC * HW;
    const char* zp = (const char*)g_zero16;

    // precompute this thread's 2 staging chunks (plane offset = 16*i, linear in tid)
    int goff[2]; bool gok[2];
    #pragma unroll
    for (int k = 0; k < 2; ++k) {
        const int i  = tid + (k << 8);
        const int rr = i / 11;
        const int q  = i - rr * 11;
        const int gy = y0 + rmin + rr;
        const int gx = x0 - 8 + (q << 2);   // 4-aligned -> chunk fully in or out
        gok[k]  = (i < nitems) && ((unsigned)gy < HH) && ((unsigned)gx <= (WW - 4));
        goff[k] = (gy * WW + gx) * 4;
    }

    float acc[3][9][4];
    #pragma unroll
    for (int t = 0; t < 3; ++t)
        #pragma unroll
        for (int o = 0; o < 9; ++o) {
            acc[t][o][0] = 0.f; acc[t][o][1] = 0.f;
            acc[t][o][2] = 0.f; acc[t][o][3] = 0.f;
        }

    // stage channel 0 -> buffer 0 (unconditional: OOB lanes fetch zeros)
    {
        const char* base = (const char*)nb;
        char* lb = (char*)planes;
        gload16(gok[0] ? base + goff[0] : zp, lb + (tid << 4));
        gload16(gok[1] ? base + goff[1] : zp, lb + ((tid + 256) << 4));
    }

    const int ci = yy - rmin;   // center row in plane; shifted row = ci + oy

    for (int c = 0; c < CC; ++c) {
        __syncthreads();   // drains DMA for channel c (vmcnt(0) before s_barrier)
        if (c + 1 < CC) {
            const char* base = (const char*)(nb + (size_t)(c + 1) * HW);
            char* lb = (char*)planes + ((c + 1) & 1) * (PLANEF * 4);
            gload16(gok[0] ? base + goff[0] : zp, lb + (tid << 4));
            gload16(gok[1] ? base + goff[1] : zp, lb + ((tid + 256) << 4));
        }
        const float* pl = planes + (c & 1) * PLANEF;
        const float4 cen4 = *(const float4*)&pl[ci * RS + xs + 8];
        const float cen[4] = {cen4.x, cen4.y, cen4.z, cen4.w};
        #pragma unroll
        for (int t = 0; t < 3; ++t) {
            if (t < NOY) {
                const float* sr = &pl[(ci + oymin + t) * RS + xs + 4];
                float sh[12];
                *(float4*)&sh[0] = *(const float4*)&sr[0];
                *(float4*)&sh[4] = *(const float4*)&sr[4];
                *(float4*)&sh[8] = *(const float4*)&sr[8];
                #pragma unroll
                for (int o = 0; o < 9; ++o)
                    #pragma unroll
                    for (int j = 0; j < 4; ++j)
                        acc[t][o][j] += cen[j] * sh[o + j];
            }
        }
    }

    // epilogue: per oy -> rowsum (shfl + LDS), colsum, direct + mirror stores
    const float inv = 1.0f / 144.0f;
    float* outb = out + (size_t)b * 81 * HW;
    const int yb  = tid / 6;    // colsum mapping (tid<180): y 0..29
    const int xgb = tid % 6;    // x-group 0..5 (float4)

    #pragma unroll
    for (int t = 0; t < 3; ++t) {
        if (t < NOY) {
            const int oy = oymin + t;
            if (t > 0) __syncthreads();   // previous colsum reads of rsum done
            #pragma unroll
            for (int o = 0; o < 9; ++o) {
                const float a0 = acc[t][o][0], a1 = acc[t][o][1];
                const float a2 = acc[t][o][2], a3 = acc[t][o][3];
                const float left  = __shfl_up(a3, 1);    // (r,g-1) corr at xs-1
                const float right = __shfl_down(a0, 1);  // (r,g+1) corr at xs+4
                if (g >= 1 && g <= 6) {
                    float4 v;
                    v.x = left + a0 + a1;
                    v.y = a0 + a1 + a2;
                    v.z = a1 + a2 + a3;
                    v.w = a2 + a3 + right;
                    *(float4*)&rsum[(o * 32 + r) * RSS + ((g - 1) << 2)] = v;
                }
            }
            __syncthreads();
            if (tid < 180) {
                const int gy = y0 + yb;
                const int gx = x0 + (xgb << 2);
                const bool dok = ((unsigned)gy < HH) && ((unsigned)gx <= (WW - 4));
                const int my = gy + oy;
                #pragma unroll
                for (int o = 0; o < 9; ++o) {
                    const float* rp = &rsum[(o * 32 + yb) * RSS + (xgb << 2)];
                    const float4 s0 = *(const float4*)&rp[0];
                    const float4 s1 = *(const float4*)&rp[RSS];
                    const float4 s2 = *(const float4*)&rp[2 * RSS];
                    float4 s;
                    s.x = (s0.x + s1.x + s2.x) * inv;
                    s.y = (s0.y + s1.y + s2.y) * inv;
                    s.z = (s0.z + s1.z + s2.z) * inv;
                    s.w = (s0.w + s1.w + s2.w) * inv;
                    if (dok)
                        *(float4*)&outb[((size_t)((oy + 4) * 9 + o)) * HW + gy * WW + gx] = s;
                    if (oy < 0 && (unsigned)my < HH) {
                        // mirror: out_{(-oy,-ox)}(gy+oy, gx+j+ox) = s[j]
                        float* mp = &outb[((size_t)((4 - oy) * 9 + (8 - o))) * HW + (size_t)my * WW];
                        const float sv[4] = {s.x, s.y, s.z, s.w};
                        const int mx0 = gx + (o - 4);
                        #pragma unroll
                        for (int j = 0; j < 4; ++j) {
                            const int mx = mx0 + j;
                            if ((unsigned)mx < WW) mp[mx] = sv[j];
                        }
                    }
                }
            }
        }
    }
}

extern "C" void kernel_launch(void* const* d_in, const int* in_sizes, int n_in,
                              void* d_out, int out_size, void* d_ws, size_t ws_size,
                              hipStream_t stream) {
    const float* noise = (const float*)d_in[0];
    float* out = (float*)d_out;
    dim3 grid(9 * 7, 2, 8);   // 9 bx x 7 by extended tiles, 2 oy-groups, 8 batches
    noise_corr_kernel<<<grid, 256, 0, stream>>>(noise, out);
}